// Round 8
// baseline (890.150 us; speedup 1.0000x reference)
//
#include <hip/hip_runtime.h>
#include <math.h>

#define N_NODES 2048
#define NNE ((long)N_NODES * N_NODES)   // elems per channel matrix
#define NNE4 (NNE / 4)

// f16 two-term split: x ~= h + l (true residual). Three MFMA products
// (hh, lh, hl) into ONE fp32 accumulator; dropped l*l term ~2^-22 relative.
// Scale chain (powers of 2, exact):
//   V0' = supd * 2^13 ; T0 = Hc@V0' scaled by 2^(10-ilogb(cn0[f])) ;
//   T1 = Hb@T0' scaled by 2^(10-ilogb(cn1[f])) ; T2 = Ha@T1' (fp32)
//   out = d*(T2*2^(i0+i1-33) + supd) + b.  Bounds HARD (mixed entries in [0,1]).
#define SUPD_SCALE 8192.0f

typedef _Float16 half4_t __attribute__((ext_vector_type(4)));
typedef _Float16 half8_t __attribute__((ext_vector_type(8)));
typedef float    floatx4 __attribute__((ext_vector_type(4)));

__device__ __forceinline__ void async_cp16(const void* g, void* l) {
  __builtin_amdgcn_global_load_lds((const __attribute__((address_space(1))) void*)g,
                                   (__attribute__((address_space(3))) void*)l,
                                   16, 0, 0);
}

__device__ __forceinline__ float colscale_from(float cn) {
  return exp2f((float)(10 - ilogbf(fmaxf(cn, 1e-37f))));
}

// ---------------- softmax of the three 4x4 weight matrices ----------------
__global__ void softmax3_k(const float* __restrict__ w1,
                           const float* __restrict__ w2,
                           const float* __restrict__ w3,
                           float* __restrict__ fw) {
  int t = threadIdx.x;
  if (t < 12) {
    const float* src = (t < 4) ? w1 : (t < 8) ? w2 : w3;
    int r = t & 3;
    float v0 = src[r * 4 + 0], v1 = src[r * 4 + 1];
    float v2 = src[r * 4 + 2], v3 = src[r * 4 + 3];
    float m = fmaxf(fmaxf(v0, v1), fmaxf(v2, v3));
    float e0 = expf(v0 - m), e1 = expf(v1 - m), e2 = expf(v2 - m), e3 = expf(v3 - m);
    float inv = 1.0f / (e0 + e1 + e2 + e3);
    fw[t * 4 + 0] = e0 * inv; fw[t * 4 + 1] = e1 * inv;
    fw[t * 4 + 2] = e2 * inv; fw[t * 4 + 3] = e3 * inv;
  }
}

// ---------------- support = X @ gcn_w  [2048,256]@[256,128] ----------------
__global__ __launch_bounds__(128)
void support_k(const float* __restrict__ X, const float* __restrict__ W,
               float* __restrict__ sup) {
  __shared__ float Xs[256];
  const int t = threadIdx.x;
  const int m = blockIdx.x;
  Xs[t]       = X[(long)m * 256 + t];
  Xs[t + 128] = X[(long)m * 256 + t + 128];
  __syncthreads();
  float acc = 0.f;
  #pragma unroll 8
  for (int k = 0; k < 256; ++k) acc = fmaf(Xs[k], W[(long)k * 128 + t], acc);
  sup[(long)m * 128 + t] = acc;
}

// -- one A pass -> Ha, Hb, Hc split row-major (lean r6 version, 28 VGPR) ----
__global__ __launch_bounds__(256)
void mix3_k(const float4* __restrict__ A4, const float* __restrict__ fw,
            _Float16* __restrict__ HaH, _Float16* __restrict__ HaL,
            _Float16* __restrict__ HbH, _Float16* __restrict__ HbL,
            _Float16* __restrict__ HcH, _Float16* __restrict__ HcL,
            int c0, int nc) {
  long idx = (long)blockIdx.x * 256 + threadIdx.x;
  float4 a0 = A4[idx];
  float4 a1 = A4[NNE4 + idx];
  float4 a2 = A4[2 * NNE4 + idx];
  float4 a3 = A4[3 * NNE4 + idx];
  for (int ci = 0; ci < nc; ++ci) {
    _Float16* OH[3] = {HaH, HbH, HcH};
    _Float16* OL[3] = {HaL, HbL, HcL};
    #pragma unroll
    for (int s = 0; s < 3; ++s) {
      const float* wv = fw + s * 16 + (c0 + ci) * 4;
      float o[4];
      o[0] = wv[0] * a0.x + wv[1] * a1.x + wv[2] * a2.x + wv[3] * a3.x;
      o[1] = wv[0] * a0.y + wv[1] * a1.y + wv[2] * a2.y + wv[3] * a3.y;
      o[2] = wv[0] * a0.z + wv[1] * a1.z + wv[2] * a2.z + wv[3] * a3.z;
      o[3] = wv[0] * a0.w + wv[1] * a1.w + wv[2] * a2.w + wv[3] * a3.w;
      half4_t h, l;
      #pragma unroll
      for (int d = 0; d < 4; ++d) {
        _Float16 hh = (_Float16)o[d];
        h[d] = hh;
        l[d] = (_Float16)(o[d] - (float)hh);
      }
      *(half4_t*)(OH[s] + (long)ci * NNE + 4 * idx) = h;
      *(half4_t*)(OL[s] + (long)ci * NNE + 4 * idx) = l;
    }
  }
}

// ---- rc[c][r] = sum_e fw3[c][e] * rowsum(A_e)[r]   (one A pass) ----------
__global__ __launch_bounds__(256)
void rc_from_A_k(const float* __restrict__ A, const float* __restrict__ fw,
                 float* __restrict__ rc) {
  const int wave = threadIdx.x >> 6, lane = threadIdx.x & 63;
  const int r = blockIdx.x * 4 + wave;
  float se[4];
  #pragma unroll
  for (int e = 0; e < 4; ++e) {
    const float4* row = (const float4*)(A + (long)e * NNE + (long)r * N_NODES);
    float s = 0.f;
    for (int j4 = lane; j4 < 512; j4 += 64) {
      float4 a = row[j4];
      s += (a.x + a.y) + (a.z + a.w);
    }
    for (int o = 32; o > 0; o >>= 1) s += __shfl_down(s, o, 64);
    se[e] = s;
  }
  if (lane == 0) {
    #pragma unroll
    for (int c = 0; c < 4; ++c)
      rc[c * N_NODES + r] = fw[32 + c * 4 + 0] * se[0] + fw[32 + c * 4 + 1] * se[1] +
                            fw[32 + c * 4 + 2] * se[2] + fw[32 + c * 4 + 3] * se[3];
  }
}

// -- vout[c][r] = sum_e fw[off+c*4+e] * (A_e @ vin[c])[r]  (fp32, one A pass)
__global__ __launch_bounds__(256)
void matvecA_k(const float* __restrict__ A, const float* __restrict__ fw, int off,
               const float* __restrict__ vin, float* __restrict__ vout) {
  __shared__ float vs[4 * 2048];
  const int t = threadIdx.x;
  for (int i = t; i < 4 * 2048; i += 256) vs[i] = vin[i];
  __syncthreads();
  const int wave = t >> 6, lane = t & 63;
  const int r = blockIdx.x * 4 + wave;
  float acc[4][4] = {{0.f}};
  #pragma unroll
  for (int e = 0; e < 4; ++e) {
    const float4* row = (const float4*)(A + (long)e * NNE + (long)r * N_NODES);
    for (int j4 = lane; j4 < 512; j4 += 64) {
      float4 a = row[j4];
      #pragma unroll
      for (int c = 0; c < 4; ++c) {
        const float4 v = *(const float4*)&vs[c * 2048 + j4 * 4];
        acc[e][c] += (a.x * v.x + a.y * v.y) + (a.z * v.z + a.w * v.w);
      }
    }
  }
  #pragma unroll
  for (int e = 0; e < 4; ++e)
    #pragma unroll
    for (int c = 0; c < 4; ++c)
      for (int o = 32; o > 0; o >>= 1) acc[e][c] += __shfl_down(acc[e][c], o, 64);
  if (lane == 0) {
    #pragma unroll
    for (int c = 0; c < 4; ++c) {
      float s = fw[off + c * 4 + 0] * acc[0][c] + fw[off + c * 4 + 1] * acc[1][c] +
                fw[off + c * 4 + 2] * acc[2][c] + fw[off + c * 4 + 3] * acc[3][c];
      vout[c * N_NODES + r] = s;
    }
  }
}

// -- fused: supd = d.*support ; dvec ; VT = (supd*2^13)^T split ; cn0 -------
__global__ __launch_bounds__(256)
void supdT_k(const float* __restrict__ sup, const float* __restrict__ deg,
             float* __restrict__ dvec, float* __restrict__ supd,
             _Float16* __restrict__ TH, _Float16* __restrict__ TL,
             float* __restrict__ cn0, int c0) {
  __shared__ _Float16 sh[32][33], sl[32][33];
  __shared__ float red[8][32];
  const int t = threadIdx.x;
  const int z = blockIdx.z;
  const int c = c0 + z;
  const int m0 = blockIdx.x * 32, f0 = blockIdx.y * 32;
  const int r0 = t >> 5, col = t & 31;
  float part = 0.f;
  #pragma unroll
  for (int m = 0; m < 4; ++m) {
    const int row = m0 + r0 + 8 * m;
    const float dm = 1.0f / sqrtf(1.0f + deg[(long)c * N_NODES + row]);
    const float v = dm * sup[(long)row * 128 + f0 + col];
    supd[(long)z * N_NODES * 128 + (long)row * 128 + f0 + col] = v;
    if (blockIdx.y == 0 && col == 0) dvec[(long)c * N_NODES + row] = dm;
    const float sv = v * SUPD_SCALE;
    _Float16 h = (_Float16)sv;
    sh[r0 + 8 * m][col] = h;
    sl[r0 + 8 * m][col] = (_Float16)(sv - (float)h);
    part += fabsf(sv);
  }
  red[r0][col] = part;
  __syncthreads();
  if (t < 32) {
    float s = 0.f;
    #pragma unroll
    for (int q = 0; q < 8; ++q) s += red[q][t];
    atomicAdd(&cn0[(long)z * 128 + f0 + t], s);
  }
  const int rr = t >> 3, cq = (t & 7) * 4;
  half4_t oh, ol;
  #pragma unroll
  for (int d = 0; d < 4; ++d) { oh[d] = sh[cq + d][rr]; ol[d] = sl[cq + d][rr]; }
  long ob = (long)z * 128 * N_NODES + (long)(f0 + rr) * N_NODES + m0 + cq;
  *(half4_t*)(TH + ob) = oh;
  *(half4_t*)(TL + ob) = ol;
}

// ---- thin split-f16 GEMM, split-K, FUSED reduction via semaphore ----------
// Each block computes a partial [128 x 128] for (kc-chunk, i-tile, z) and
// stores fp32 partials; the LAST block per (z, i-tile) sums kc partials and
// performs the stage epilogue:
//   stage 0/1: colscale by cn_in, split to f16, LDS-transpose -> TH/TL,
//              (stage 0 also accumulates cn_out)
//   stage 2:   final: out = relu(dvec*(sum*2^(e0+e1-33) + supd) + bias)
__global__ __launch_bounds__(256, 2)
void gemm_thin_k(const _Float16* __restrict__ AH, const _Float16* __restrict__ AL,
                 const _Float16* __restrict__ BH, const _Float16* __restrict__ BL,
                 float* __restrict__ C, int kper, int stage,
                 const float* __restrict__ cn_in, float* __restrict__ cn_out,
                 _Float16* __restrict__ TH, _Float16* __restrict__ TL,
                 const float* __restrict__ supd, const float* __restrict__ dvec,
                 const float* __restrict__ cn0, const float* __restrict__ cn1,
                 const float* __restrict__ bias, float* __restrict__ out,
                 int c0, int* __restrict__ cnt) {
  __shared__ __align__(16) _Float16 smem[2][4][128 * 32];

  const int t = threadIdx.x;
  const int lane = t & 63;
  const int w = t >> 6;
  const int wm = w >> 1, wn = w & 1;
  const int i0 = blockIdx.y * 128;
  const int koff = blockIdx.x * kper;
  const int z = blockIdx.z;
  const long zoA = (long)z * NNE;
  const long zoB = (long)z * 128 * N_NODES;

  const _Float16* gsrc = (w == 0) ? (AH + zoA) : (w == 1) ? (AL + zoA)
                       : (w == 2) ? (BH + zoB) : (BL + zoB);
  const int rbase = (w < 2) ? i0 : 0;
  const int kc_st = (((lane & 3) - ((lane >> 3) & 3)) & 3) * 8;
  const _Float16* gp = gsrc + (long)(rbase + (lane >> 2)) * N_NODES + koff + kc_st;

  const int fr = lane & 15;
  const int fkz = (((lane >> 4) + (fr >> 1)) & 3) * 8;
  const int aoff = (wm * 64 + fr) * 32 + fkz;
  const int boff = (wn * 64 + fr) * 32 + fkz;

  floatx4 acc[4][4];
  #pragma unroll
  for (int i = 0; i < 4; ++i)
    #pragma unroll
    for (int j = 0; j < 4; ++j) {
      floatx4 zz = {0.f, 0.f, 0.f, 0.f};
      acc[i][j] = zz;
    }

  {
    _Float16* lb = &smem[0][w][0];
    #pragma unroll
    for (int q = 0; q < 8; ++q)
      async_cp16(gp + (long)q * (16 * N_NODES), lb + q * 512);
    gp += 32;
  }
  __syncthreads();

  const int NKI = kper / 32;
  for (int kt = 0; kt < NKI; ++kt) {
    const int p = kt & 1;
    if (kt + 1 < NKI) {
      _Float16* lb = &smem[p ^ 1][w][0];
      #pragma unroll
      for (int q = 0; q < 8; ++q)
        async_cp16(gp + (long)q * (16 * N_NODES), lb + q * 512);
      gp += 32;
    }
    const _Float16* base = &smem[p][0][0];
    half8_t ah[4], al[4], bh[4], bl[4];
    #pragma unroll
    for (int mt = 0; mt < 4; ++mt) {
      ah[mt] = *(const half8_t*)(base + aoff + mt * 512);
      al[mt] = *(const half8_t*)(base + 4096 + aoff + mt * 512);
    }
    #pragma unroll
    for (int nt = 0; nt < 4; ++nt) {
      bh[nt] = *(const half8_t*)(base + 8192 + boff + nt * 512);
      bl[nt] = *(const half8_t*)(base + 12288 + boff + nt * 512);
    }
    #pragma unroll
    for (int mt = 0; mt < 4; ++mt)
      #pragma unroll
      for (int nt = 0; nt < 4; ++nt) {
        acc[mt][nt] = __builtin_amdgcn_mfma_f32_16x16x32_f16(ah[mt], bh[nt], acc[mt][nt], 0, 0, 0);
        acc[mt][nt] = __builtin_amdgcn_mfma_f32_16x16x32_f16(al[mt], bh[nt], acc[mt][nt], 0, 0, 0);
        acc[mt][nt] = __builtin_amdgcn_mfma_f32_16x16x32_f16(ah[mt], bl[nt], acc[mt][nt], 0, 0, 0);
      }
    __syncthreads();
  }

  // ---- write fp32 partials ----
  const int er = (lane >> 4) * 4;
  const int ec = lane & 15;
  const long stepP = (long)gridDim.z * N_NODES * 128;
  const long basP = ((long)z * N_NODES + i0) * 128;
  float* Cb = C + (long)blockIdx.x * stepP + basP;
  #pragma unroll
  for (int mt = 0; mt < 4; ++mt)
    #pragma unroll
    for (int nt = 0; nt < 4; ++nt) {
      const int f = wn * 64 + nt * 16 + ec;
      #pragma unroll
      for (int r = 0; r < 4; ++r)
        Cb[(long)(wm * 64 + mt * 16 + er + r) * 128 + f] = acc[mt][nt][r];
    }

  // ---- semaphore: last block per (z, i-tile) does the reduction ----
  __threadfence();
  __shared__ int lastf;
  __syncthreads();
  if (t == 0) {
    int old = atomicAdd(&cnt[(z << 4) + blockIdx.y], 1);
    lastf = (old == (int)gridDim.x - 1) ? 1 : 0;
  }
  __syncthreads();
  if (!lastf) return;
  __threadfence();

  const int kc = gridDim.x;

  if (stage == 2) {
    // final epilogue over this i-tile
    const int c = c0 + z;
    const int rr = t >> 5;           // 0..7
    const int f4 = (t & 31) * 4;
    float inv[4];
    #pragma unroll
    for (int d = 0; d < 4; ++d) {
      int e0 = ilogbf(fmaxf(cn0[(long)z * 128 + f4 + d], 1e-37f));
      int e1 = ilogbf(fmaxf(cn1[(long)z * 128 + f4 + d], 1e-37f));
      inv[d] = exp2f((float)(e0 + e1 - 33));
    }
    for (int m = 0; m < 16; ++m) {
      const int i = i0 + rr + 8 * m;
      long idx = basP + (long)(rr + 8 * m) * 128 + f4;
      float4 sm = {0.f, 0.f, 0.f, 0.f};
      for (int q = 0; q < kc; ++q) {
        const float4 p = *(const float4*)&C[idx + (long)q * stepP];
        sm.x += p.x; sm.y += p.y; sm.z += p.z; sm.w += p.w;
      }
      const float dn = dvec[(long)c * N_NODES + i];
      const float4 sp = *(const float4*)&supd[((long)z * N_NODES + i) * 128 + f4];
      float4 o;
      o.x = fmaxf(dn * (sm.x * inv[0] + sp.x) + bias[f4 + 0], 0.f);
      o.y = fmaxf(dn * (sm.y * inv[1] + sp.y) + bias[f4 + 1], 0.f);
      o.z = fmaxf(dn * (sm.z * inv[2] + sp.z) + bias[f4 + 2], 0.f);
      o.w = fmaxf(dn * (sm.w * inv[3] + sp.w) + bias[f4 + 3], 0.f);
      *(float4*)&out[(long)i * 512 + c * 128 + f4] = o;
    }
    return;
  }

  // stages 0/1: combine kc partials, colscale, split, transpose -> TH/TL
  _Float16* sh = &smem[0][0][0];          // [32][33]
  _Float16* sl = sh + 32 * 33;
  float* red = (float*)(sl + 32 * 33 + 2);  // 8x32, 4B aligned
  const int r0 = t >> 5, col = t & 31;
  const int rr2 = t >> 3, cq = (t & 7) * 4;
  for (int fb = 0; fb < 4; ++fb) {
    const int f = fb * 32 + col;
    const float s = colscale_from(cn_in[(long)z * 128 + f]);
    float partabs = 0.f;
    for (int jb = 0; jb < 4; ++jb) {
      __syncthreads();
      #pragma unroll
      for (int m = 0; m < 4; ++m) {
        const int jr = jb * 32 + r0 + 8 * m;      // local row 0..127
        long idx = basP + (long)jr * 128 + fb * 32 + col;
        float v = 0.f;
        for (int q = 0; q < kc; ++q) v += C[idx + (long)q * stepP];
        v *= s;
        _Float16 h = (_Float16)v;
        sh[(r0 + 8 * m) * 33 + col] = h;
        sl[(r0 + 8 * m) * 33 + col] = (_Float16)(v - (float)h);
        partabs += fabsf(v);
      }
      __syncthreads();
      half4_t oh, ol;
      #pragma unroll
      for (int d = 0; d < 4; ++d) {
        oh[d] = sh[(cq + d) * 33 + rr2];
        ol[d] = sl[(cq + d) * 33 + rr2];
      }
      long ob = (long)z * 128 * N_NODES + (long)(fb * 32 + rr2) * N_NODES +
                (i0 + jb * 32) + cq;
      *(half4_t*)(TH + ob) = oh;
      *(half4_t*)(TL + ob) = ol;
    }
    if (cn_out) {
      __syncthreads();
      red[r0 * 32 + col] = partabs;
      __syncthreads();
      if (t < 32) {
        float ssum = 0.f;
        #pragma unroll
        for (int q = 0; q < 8; ++q) ssum += red[q * 32 + t];
        atomicAdd(&cn_out[(long)z * 128 + fb * 32 + t], ssum);
      }
    }
  }
}

extern "C" void kernel_launch(void* const* d_in, const int* in_sizes, int n_in,
                              void* d_out, int out_size, void* d_ws, size_t ws_size,
                              hipStream_t stream) {
  const float* A  = (const float*)d_in[0];
  const float* X  = (const float*)d_in[1];
  const float* w1 = (const float*)d_in[2];
  const float* w2 = (const float*)d_in[3];
  const float* w3 = (const float*)d_in[4];
  const float* w3b = (const float*)d_in[4];
  (void)w3b;
  const float* gw = (const float*)d_in[5];
  const float* gb = (const float*)d_in[6];
  float* out = (float*)d_out;

  // ---- workspace layout ----
  float* ws   = (float*)d_ws;
  float* fw   = ws;                        // 64
  float* rc   = fw + 64;                   // 4*2048
  float* v1   = rc + 4 * N_NODES;          // 4*2048
  float* deg  = v1 + 4 * N_NODES;          // 4*2048
  float* dvec = deg + 4 * N_NODES;         // 4*2048
  float* sup  = dvec + 4 * N_NODES;        // 2048*128
  float* dyn  = sup + (long)N_NODES * 128;

  const long fixed_f = 64 + 16 * N_NODES + (long)N_NODES * 128;
  auto need = [&](long nc, long kc) {
    long f32 = fixed_f + 2 * nc * 128 + 3 * nc * 16 +
               nc * N_NODES * 128 + kc * nc * N_NODES * 128;
    long f16 = 6 * nc * NNE + 6 * nc * 128 * N_NODES;
    return f32 * 4 + f16 * 2;
  };
  int nc = 1, kc = 8;
  if ((long)ws_size >= need(4, 8))      { nc = 4; kc = 8; }
  else if ((long)ws_size >= need(4, 4)) { nc = 4; kc = 4; }
  else if ((long)ws_size >= need(2, 8)) { nc = 2; kc = 8; }
  else if ((long)ws_size >= need(2, 4)) { nc = 2; kc = 4; }
  else                                  { nc = 1; kc = 8; }
  const int kper = N_NODES / kc;

  float* cn0  = dyn;                                   // [nc][128]
  float* cn1  = cn0 + (long)nc * 128;                  // [nc][128]
  int*   cnt  = (int*)(cn1 + (long)nc * 128);          // [3][nc*16]
  float* supd = (float*)(cnt + 3L * nc * 16);          // [nc][2048][128]
  float* Mtmp = supd + (long)nc * N_NODES * 128;       // [kc][nc][2048][128]
  _Float16* arena = (_Float16*)(Mtmp + (long)kc * nc * N_NODES * 128);
  _Float16* HaH = arena;
  _Float16* HaL = HaH + (long)nc * NNE;
  _Float16* HbH = HaL + (long)nc * NNE;
  _Float16* HbL = HbH + (long)nc * NNE;
  _Float16* HcH = HbL + (long)nc * NNE;
  _Float16* HcL = HcH + (long)nc * NNE;
  _Float16* VTH = HcL + (long)nc * NNE;                // [nc][128][2048]
  _Float16* VTL = VTH + (long)nc * 128 * N_NODES;
  _Float16* T0H = VTL + (long)nc * 128 * N_NODES;
  _Float16* T0L = T0H + (long)nc * 128 * N_NODES;
  _Float16* T1H = T0L + (long)nc * 128 * N_NODES;
  _Float16* T1L = T1H + (long)nc * 128 * N_NODES;

  softmax3_k<<<1, 64, 0, stream>>>(w1, w2, w3, fw);
  support_k<<<N_NODES, 128, 0, stream>>>(X, gw, sup);
  // deg chain: rc = Hc@1 ; v1 = Hb@rc ; deg = Ha@v1 (all channels, fp32)
  rc_from_A_k<<<N_NODES / 4, 256, 0, stream>>>(A, fw, rc);
  matvecA_k<<<N_NODES / 4, 256, 0, stream>>>(A, fw, 16, rc, v1);
  matvecA_k<<<N_NODES / 4, 256, 0, stream>>>(A, fw, 0, v1, deg);

  for (int c0 = 0; c0 < 4; c0 += nc) {
    // zero cn0, cn1, and the 3 stage semaphore arrays (contiguous)
    hipMemsetAsync(cn0, 0,
                   (2L * nc * 128) * sizeof(float) + 3L * nc * 16 * sizeof(int),
                   stream);
    // Ha/Hb/Hc split row-major, one A pass (lean)
    mix3_k<<<(int)(NNE4 / 256), 256, 0, stream>>>((const float4*)A, fw,
                                                  HaH, HaL, HbH, HbL, HcH, HcL,
                                                  c0, nc);
    // supd + dvec + VT split + cn0, fused
    supdT_k<<<dim3(64, 4, nc), 256, 0, stream>>>(sup, deg, dvec, supd,
                                                 VTH, VTL, cn0, c0);
    // T0 = Hc @ VT  (fused combine -> T0', cn1)
    gemm_thin_k<<<dim3(kc, 16, nc), 256, 0, stream>>>(
        HcH, HcL, VTH, VTL, Mtmp, kper, 0, cn0, cn1, T0H, T0L,
        nullptr, nullptr, nullptr, nullptr, nullptr, nullptr, c0, cnt);
    // T1 = Hb @ T0'  (fused combine -> T1')
    gemm_thin_k<<<dim3(kc, 16, nc), 256, 0, stream>>>(
        HbH, HbL, T0H, T0L, Mtmp, kper, 1, cn1, nullptr, T1H, T1L,
        nullptr, nullptr, nullptr, nullptr, nullptr, nullptr, c0, cnt + nc * 16);
    // T2 = Ha @ T1'  (fused final epilogue -> out)
    gemm_thin_k<<<dim3(kc, 16, nc), 256, 0, stream>>>(
        HaH, HaL, T1H, T1L, Mtmp, kper, 2, nullptr, nullptr, nullptr, nullptr,
        supd, dvec, cn0, cn1, gb, out, c0, cnt + 2 * nc * 16);
  }
}

// Round 9
// 322.312 us; speedup vs baseline: 2.7618x; 2.7618x over previous
//
#include <hip/hip_runtime.h>
#include <math.h>

#define N_NODES 2048
#define NNE ((long)N_NODES * N_NODES)   // elems per channel matrix
#define NNE4 (NNE / 4)

// f16 two-term split: x ~= h + l (true residual). Three MFMA products
// (hh, lh, hl) into ONE fp32 accumulator; dropped l*l term ~2^-22 relative.
// Scale chain (powers of 2, exact):
//   V0' = supd * 2^13 ; T0 = Hc@V0' scaled by 2^(10-ilogb(cn0[f])) ;
//   T1 = Hb@T0' scaled by 2^(10-ilogb(cn1[f])) ; T2 = Ha@T1' (fp32)
//   out = d*(T2*2^(i0+i1-33) + supd) + b.  Bounds HARD (mixed entries in [0,1]).
// NOTE (r8 lesson): cross-XCD semaphore reductions inside one kernel are
// catastrophically slow on gfx950 (non-coherent per-XCD L2; device-scope
// fence forces HBM round-trips). Keep split-K combine as a separate kernel.
#define SUPD_SCALE 8192.0f

typedef _Float16 half4_t __attribute__((ext_vector_type(4)));
typedef _Float16 half8_t __attribute__((ext_vector_type(8)));
typedef float    floatx4 __attribute__((ext_vector_type(4)));

__device__ __forceinline__ void async_cp16(const void* g, void* l) {
  __builtin_amdgcn_global_load_lds((const __attribute__((address_space(1))) void*)g,
                                   (__attribute__((address_space(3))) void*)l,
                                   16, 0, 0);
}

__device__ __forceinline__ float colscale_from(float cn) {
  return exp2f((float)(10 - ilogbf(fmaxf(cn, 1e-37f))));
}

// ---------------- softmax of the three 4x4 weight matrices ----------------
__global__ void softmax3_k(const float* __restrict__ w1,
                           const float* __restrict__ w2,
                           const float* __restrict__ w3,
                           float* __restrict__ fw) {
  int t = threadIdx.x;
  if (t < 12) {
    const float* src = (t < 4) ? w1 : (t < 8) ? w2 : w3;
    int r = t & 3;
    float v0 = src[r * 4 + 0], v1 = src[r * 4 + 1];
    float v2 = src[r * 4 + 2], v3 = src[r * 4 + 3];
    float m = fmaxf(fmaxf(v0, v1), fmaxf(v2, v3));
    float e0 = expf(v0 - m), e1 = expf(v1 - m), e2 = expf(v2 - m), e3 = expf(v3 - m);
    float inv = 1.0f / (e0 + e1 + e2 + e3);
    fw[t * 4 + 0] = e0 * inv; fw[t * 4 + 1] = e1 * inv;
    fw[t * 4 + 2] = e2 * inv; fw[t * 4 + 3] = e3 * inv;
  }
}

// ---------------- support = X @ gcn_w  [2048,256]@[256,128] ----------------
__global__ __launch_bounds__(128)
void support_k(const float* __restrict__ X, const float* __restrict__ W,
               float* __restrict__ sup) {
  __shared__ float Xs[256];
  const int t = threadIdx.x;
  const int m = blockIdx.x;
  Xs[t]       = X[(long)m * 256 + t];
  Xs[t + 128] = X[(long)m * 256 + t + 128];
  __syncthreads();
  float acc = 0.f;
  #pragma unroll 8
  for (int k = 0; k < 256; ++k) acc = fmaf(Xs[k], W[(long)k * 128 + t], acc);
  sup[(long)m * 128 + t] = acc;
}

// -- one A pass -> Ha, Hb, Hc split row-major (lean, 28 VGPR, BW-roofline) --
__global__ __launch_bounds__(256)
void mix3_k(const float4* __restrict__ A4, const float* __restrict__ fw,
            _Float16* __restrict__ HaH, _Float16* __restrict__ HaL,
            _Float16* __restrict__ HbH, _Float16* __restrict__ HbL,
            _Float16* __restrict__ HcH, _Float16* __restrict__ HcL,
            int c0, int nc) {
  long idx = (long)blockIdx.x * 256 + threadIdx.x;
  float4 a0 = A4[idx];
  float4 a1 = A4[NNE4 + idx];
  float4 a2 = A4[2 * NNE4 + idx];
  float4 a3 = A4[3 * NNE4 + idx];
  for (int ci = 0; ci < nc; ++ci) {
    _Float16* OH[3] = {HaH, HbH, HcH};
    _Float16* OL[3] = {HaL, HbL, HcL};
    #pragma unroll
    for (int s = 0; s < 3; ++s) {
      const float* wv = fw + s * 16 + (c0 + ci) * 4;
      float o[4];
      o[0] = wv[0] * a0.x + wv[1] * a1.x + wv[2] * a2.x + wv[3] * a3.x;
      o[1] = wv[0] * a0.y + wv[1] * a1.y + wv[2] * a2.y + wv[3] * a3.y;
      o[2] = wv[0] * a0.z + wv[1] * a1.z + wv[2] * a2.z + wv[3] * a3.z;
      o[3] = wv[0] * a0.w + wv[1] * a1.w + wv[2] * a2.w + wv[3] * a3.w;
      half4_t h, l;
      #pragma unroll
      for (int d = 0; d < 4; ++d) {
        _Float16 hh = (_Float16)o[d];
        h[d] = hh;
        l[d] = (_Float16)(o[d] - (float)hh);
      }
      *(half4_t*)(OH[s] + (long)ci * NNE + 4 * idx) = h;
      *(half4_t*)(OL[s] + (long)ci * NNE + 4 * idx) = l;
    }
  }
}

// ---- rc[c][r] = sum_e fw3[c][e] * rowsum(A_e)[r]   (one A pass) ----------
__global__ __launch_bounds__(256)
void rc_from_A_k(const float* __restrict__ A, const float* __restrict__ fw,
                 float* __restrict__ rc) {
  const int wave = threadIdx.x >> 6, lane = threadIdx.x & 63;
  const int r = blockIdx.x * 4 + wave;
  float se[4];
  #pragma unroll
  for (int e = 0; e < 4; ++e) {
    const float4* row = (const float4*)(A + (long)e * NNE + (long)r * N_NODES);
    float s = 0.f;
    for (int j4 = lane; j4 < 512; j4 += 64) {
      float4 a = row[j4];
      s += (a.x + a.y) + (a.z + a.w);
    }
    for (int o = 32; o > 0; o >>= 1) s += __shfl_down(s, o, 64);
    se[e] = s;
  }
  if (lane == 0) {
    #pragma unroll
    for (int c = 0; c < 4; ++c)
      rc[c * N_NODES + r] = fw[32 + c * 4 + 0] * se[0] + fw[32 + c * 4 + 1] * se[1] +
                            fw[32 + c * 4 + 2] * se[2] + fw[32 + c * 4 + 3] * se[3];
  }
}

// -- vout[c][r] = sum_e fw[off+c*4+e] * (A_e @ vin[c])[r]  (fp32, one A pass)
__global__ __launch_bounds__(256)
void matvecA_k(const float* __restrict__ A, const float* __restrict__ fw, int off,
               const float* __restrict__ vin, float* __restrict__ vout) {
  __shared__ float vs[4 * 2048];
  const int t = threadIdx.x;
  for (int i = t; i < 4 * 2048; i += 256) vs[i] = vin[i];
  __syncthreads();
  const int wave = t >> 6, lane = t & 63;
  const int r = blockIdx.x * 4 + wave;
  float acc[4][4] = {{0.f}};
  #pragma unroll
  for (int e = 0; e < 4; ++e) {
    const float4* row = (const float4*)(A + (long)e * NNE + (long)r * N_NODES);
    for (int j4 = lane; j4 < 512; j4 += 64) {
      float4 a = row[j4];
      #pragma unroll
      for (int c = 0; c < 4; ++c) {
        const float4 v = *(const float4*)&vs[c * 2048 + j4 * 4];
        acc[e][c] += (a.x * v.x + a.y * v.y) + (a.z * v.z + a.w * v.w);
      }
    }
  }
  #pragma unroll
  for (int e = 0; e < 4; ++e)
    #pragma unroll
    for (int c = 0; c < 4; ++c)
      for (int o = 32; o > 0; o >>= 1) acc[e][c] += __shfl_down(acc[e][c], o, 64);
  if (lane == 0) {
    #pragma unroll
    for (int c = 0; c < 4; ++c) {
      float s = fw[off + c * 4 + 0] * acc[0][c] + fw[off + c * 4 + 1] * acc[1][c] +
                fw[off + c * 4 + 2] * acc[2][c] + fw[off + c * 4 + 3] * acc[3][c];
      vout[c * N_NODES + r] = s;
    }
  }
}

// -- fused: supd = d.*support ; dvec ; VT = (supd*2^13)^T split ; cn0 -------
__global__ __launch_bounds__(256)
void supdT_k(const float* __restrict__ sup, const float* __restrict__ deg,
             float* __restrict__ dvec, float* __restrict__ supd,
             _Float16* __restrict__ TH, _Float16* __restrict__ TL,
             float* __restrict__ cn0, int c0) {
  __shared__ _Float16 sh[32][33], sl[32][33];
  __shared__ float red[8][32];
  const int t = threadIdx.x;
  const int z = blockIdx.z;
  const int c = c0 + z;
  const int m0 = blockIdx.x * 32, f0 = blockIdx.y * 32;
  const int r0 = t >> 5, col = t & 31;
  float part = 0.f;
  #pragma unroll
  for (int m = 0; m < 4; ++m) {
    const int row = m0 + r0 + 8 * m;
    const float dm = 1.0f / sqrtf(1.0f + deg[(long)c * N_NODES + row]);
    const float v = dm * sup[(long)row * 128 + f0 + col];
    supd[(long)z * N_NODES * 128 + (long)row * 128 + f0 + col] = v;
    if (blockIdx.y == 0 && col == 0) dvec[(long)c * N_NODES + row] = dm;
    const float sv = v * SUPD_SCALE;
    _Float16 h = (_Float16)sv;
    sh[r0 + 8 * m][col] = h;
    sl[r0 + 8 * m][col] = (_Float16)(sv - (float)h);
    part += fabsf(sv);
  }
  red[r0][col] = part;
  __syncthreads();
  if (t < 32) {
    float s = 0.f;
    #pragma unroll
    for (int q = 0; q < 8; ++q) s += red[q][t];
    atomicAdd(&cn0[(long)z * 128 + f0 + t], s);
  }
  const int rr = t >> 3, cq = (t & 7) * 4;
  half4_t oh, ol;
  #pragma unroll
  for (int d = 0; d < 4; ++d) { oh[d] = sh[cq + d][rr]; ol[d] = sl[cq + d][rr]; }
  long ob = (long)z * 128 * N_NODES + (long)(f0 + rr) * N_NODES + m0 + cq;
  *(half4_t*)(TH + ob) = oh;
  *(half4_t*)(TL + ob) = ol;
}

// ---- thin split-f16 GEMM, split-K: partials[kc][z][i][f] = A[z]@B[z] ------
__global__ __launch_bounds__(256, 2)
void gemm_thin_k(const _Float16* __restrict__ AH, const _Float16* __restrict__ AL,
                 const _Float16* __restrict__ BH, const _Float16* __restrict__ BL,
                 float* __restrict__ C, int kper) {
  __shared__ __align__(16) _Float16 smem[2][4][128 * 32];

  const int t = threadIdx.x;
  const int lane = t & 63;
  const int w = t >> 6;
  const int wm = w >> 1, wn = w & 1;
  const int i0 = blockIdx.y * 128;
  const int koff = blockIdx.x * kper;
  const int z = blockIdx.z;
  const long zoA = (long)z * NNE;
  const long zoB = (long)z * 128 * N_NODES;

  const _Float16* gsrc = (w == 0) ? (AH + zoA) : (w == 1) ? (AL + zoA)
                       : (w == 2) ? (BH + zoB) : (BL + zoB);
  const int rbase = (w < 2) ? i0 : 0;
  const int kc_st = (((lane & 3) - ((lane >> 3) & 3)) & 3) * 8;
  const _Float16* gp = gsrc + (long)(rbase + (lane >> 2)) * N_NODES + koff + kc_st;

  const int fr = lane & 15;
  const int fkz = (((lane >> 4) + (fr >> 1)) & 3) * 8;
  const int aoff = (wm * 64 + fr) * 32 + fkz;
  const int boff = (wn * 64 + fr) * 32 + fkz;

  floatx4 acc[4][4];
  #pragma unroll
  for (int i = 0; i < 4; ++i)
    #pragma unroll
    for (int j = 0; j < 4; ++j) {
      floatx4 zz = {0.f, 0.f, 0.f, 0.f};
      acc[i][j] = zz;
    }

  {
    _Float16* lb = &smem[0][w][0];
    #pragma unroll
    for (int q = 0; q < 8; ++q)
      async_cp16(gp + (long)q * (16 * N_NODES), lb + q * 512);
    gp += 32;
  }
  __syncthreads();

  const int NKI = kper / 32;
  for (int kt = 0; kt < NKI; ++kt) {
    const int p = kt & 1;
    if (kt + 1 < NKI) {
      _Float16* lb = &smem[p ^ 1][w][0];
      #pragma unroll
      for (int q = 0; q < 8; ++q)
        async_cp16(gp + (long)q * (16 * N_NODES), lb + q * 512);
      gp += 32;
    }
    const _Float16* base = &smem[p][0][0];
    half8_t ah[4], al[4], bh[4], bl[4];
    #pragma unroll
    for (int mt = 0; mt < 4; ++mt) {
      ah[mt] = *(const half8_t*)(base + aoff + mt * 512);
      al[mt] = *(const half8_t*)(base + 4096 + aoff + mt * 512);
    }
    #pragma unroll
    for (int nt = 0; nt < 4; ++nt) {
      bh[nt] = *(const half8_t*)(base + 8192 + boff + nt * 512);
      bl[nt] = *(const half8_t*)(base + 12288 + boff + nt * 512);
    }
    #pragma unroll
    for (int mt = 0; mt < 4; ++mt)
      #pragma unroll
      for (int nt = 0; nt < 4; ++nt) {
        acc[mt][nt] = __builtin_amdgcn_mfma_f32_16x16x32_f16(ah[mt], bh[nt], acc[mt][nt], 0, 0, 0);
        acc[mt][nt] = __builtin_amdgcn_mfma_f32_16x16x32_f16(al[mt], bh[nt], acc[mt][nt], 0, 0, 0);
        acc[mt][nt] = __builtin_amdgcn_mfma_f32_16x16x32_f16(ah[mt], bl[nt], acc[mt][nt], 0, 0, 0);
      }
    __syncthreads();
  }

  const int er = (lane >> 4) * 4;
  const int ec = lane & 15;
  float* Cb = C + ((long)(blockIdx.x * gridDim.z + z) * N_NODES + i0) * 128;
  #pragma unroll
  for (int mt = 0; mt < 4; ++mt)
    #pragma unroll
    for (int nt = 0; nt < 4; ++nt) {
      const int f = wn * 64 + nt * 16 + ec;
      #pragma unroll
      for (int r = 0; r < 4; ++r)
        Cb[(long)(wm * 64 + mt * 16 + er + r) * 128 + f] = acc[mt][nt][r];
    }
}

// -- T'[z][f][j] = split( (sum_kc P[kc][z][j][f]) * s(cn_in[z][f]) ) --------
__global__ __launch_bounds__(256)
void combineT_k(const float* __restrict__ P, int nc, int kc,
                const float* __restrict__ cn_in, float* __restrict__ cn_out,
                _Float16* __restrict__ TH, _Float16* __restrict__ TL) {
  __shared__ _Float16 sh[32][33], sl[32][33];
  __shared__ float red[8][32];
  const int t = threadIdx.x;
  const int z = blockIdx.z;
  const int j0 = blockIdx.x * 32, f0 = blockIdx.y * 32;
  const int r0 = t >> 5, col = t & 31;
  const float s = colscale_from(cn_in[(long)z * 128 + f0 + col]);
  const long step = (long)nc * N_NODES * 128;
  float part = 0.f;
  #pragma unroll
  for (int m = 0; m < 4; ++m) {
    long idx = ((long)z * N_NODES + j0 + r0 + 8 * m) * 128 + f0 + col;
    float v = 0.f;
    for (int q = 0; q < kc; ++q) v += P[idx + q * step];
    v *= s;
    _Float16 h = (_Float16)v;
    sh[r0 + 8 * m][col] = h;
    sl[r0 + 8 * m][col] = (_Float16)(v - (float)h);
    part += fabsf(v);
  }
  if (cn_out) red[r0][col] = part;
  __syncthreads();
  if (cn_out && t < 32) {
    float ss = 0.f;
    #pragma unroll
    for (int q = 0; q < 8; ++q) ss += red[q][t];
    atomicAdd(&cn_out[(long)z * 128 + f0 + t], ss);
  }
  const int rr = t >> 3, cq = (t & 7) * 4;
  half4_t oh, ol;
  #pragma unroll
  for (int d = 0; d < 4; ++d) { oh[d] = sh[cq + d][rr]; ol[d] = sl[cq + d][rr]; }
  long ob = (long)z * 128 * N_NODES + (long)(f0 + rr) * N_NODES + j0 + cq;
  *(half4_t*)(TH + ob) = oh;
  *(half4_t*)(TL + ob) = ol;
}

// --- out[i][c*128+f] = relu( d*( T2sum * 2^(i0+i1-33) + supd ) + b ) -------
__global__ __launch_bounds__(256)
void final_k(const float4* __restrict__ T2, const float4* __restrict__ supd,
             const float* __restrict__ dvec, const float* __restrict__ cn0,
             const float* __restrict__ cn1, const float* __restrict__ bias,
             float* __restrict__ out, int c0, int nc, int kc) {
  const int t = threadIdx.x;
  const int z = blockIdx.y;
  const int c = c0 + z;
  const int idx = blockIdx.x * 256 + t;
  const int i = idx >> 5;
  const int fq = (idx & 31) * 4;
  const long step4 = (long)nc * N_NODES * 32;
  long b4 = (long)z * N_NODES * 32 + idx;
  float4 sm = {0.f, 0.f, 0.f, 0.f};
  for (int q = 0; q < kc; ++q) {
    float4 p = T2[b4 + q * step4];
    sm.x += p.x; sm.y += p.y; sm.z += p.z; sm.w += p.w;
  }
  float4 sp = supd[(long)z * N_NODES * 32 + idx];
  const float dn = dvec[(long)c * N_NODES + i];
  float inv[4];
  #pragma unroll
  for (int d = 0; d < 4; ++d) {
    int e0 = ilogbf(fmaxf(cn0[(long)z * 128 + fq + d], 1e-37f));
    int e1 = ilogbf(fmaxf(cn1[(long)z * 128 + fq + d], 1e-37f));
    inv[d] = exp2f((float)(e0 + e1 - 33));
  }
  float4 o;
  o.x = fmaxf(dn * (sm.x * inv[0] + sp.x) + bias[fq + 0], 0.f);
  o.y = fmaxf(dn * (sm.y * inv[1] + sp.y) + bias[fq + 1], 0.f);
  o.z = fmaxf(dn * (sm.z * inv[2] + sp.z) + bias[fq + 2], 0.f);
  o.w = fmaxf(dn * (sm.w * inv[3] + sp.w) + bias[fq + 3], 0.f);
  *(float4*)(out + (long)i * 512 + c * 128 + fq) = o;
}

extern "C" void kernel_launch(void* const* d_in, const int* in_sizes, int n_in,
                              void* d_out, int out_size, void* d_ws, size_t ws_size,
                              hipStream_t stream) {
  const float* A  = (const float*)d_in[0];
  const float* X  = (const float*)d_in[1];
  const float* w1 = (const float*)d_in[2];
  const float* w2 = (const float*)d_in[3];
  const float* w3 = (const float*)d_in[4];
  const float* gw = (const float*)d_in[5];
  const float* gb = (const float*)d_in[6];
  float* out = (float*)d_out;

  // ---- workspace layout ----
  float* ws   = (float*)d_ws;
  float* fw   = ws;                        // 64
  float* rc   = fw + 64;                   // 4*2048
  float* v1   = rc + 4 * N_NODES;          // 4*2048
  float* deg  = v1 + 4 * N_NODES;          // 4*2048
  float* dvec = deg + 4 * N_NODES;         // 4*2048
  float* sup  = dvec + 4 * N_NODES;        // 2048*128
  float* dyn  = sup + (long)N_NODES * 128;

  const long fixed_f = 64 + 16 * N_NODES + (long)N_NODES * 128;
  const int kc = 4;
  auto need = [&](long nc) {
    long f32 = fixed_f + 2 * nc * 128 + nc * N_NODES * 128 +
               (long)kc * nc * N_NODES * 128;
    long f16 = 6 * nc * NNE + 6 * nc * 128 * N_NODES;
    return f32 * 4 + f16 * 2;
  };
  int nc = 1;
  if ((long)ws_size >= need(4)) nc = 4;
  else if ((long)ws_size >= need(2)) nc = 2;
  const int kper = N_NODES / kc;

  float* cn0  = dyn;                                   // [nc][128]
  float* cn1  = cn0 + (long)nc * 128;                  // [nc][128]
  float* supd = cn1 + (long)nc * 128;                  // [nc][2048][128]
  float* Mtmp = supd + (long)nc * N_NODES * 128;       // [kc][nc][2048][128]
  _Float16* arena = (_Float16*)(Mtmp + (long)kc * nc * N_NODES * 128);
  _Float16* HaH = arena;
  _Float16* HaL = HaH + (long)nc * NNE;
  _Float16* HbH = HaL + (long)nc * NNE;
  _Float16* HbL = HbH + (long)nc * NNE;
  _Float16* HcH = HbL + (long)nc * NNE;
  _Float16* HcL = HcH + (long)nc * NNE;
  _Float16* VTH = HcL + (long)nc * NNE;                // [nc][128][2048]
  _Float16* VTL = VTH + (long)nc * 128 * N_NODES;
  _Float16* T0H = VTL + (long)nc * 128 * N_NODES;
  _Float16* T0L = T0H + (long)nc * 128 * N_NODES;
  _Float16* T1H = T0L + (long)nc * 128 * N_NODES;
  _Float16* T1L = T1H + (long)nc * 128 * N_NODES;

  softmax3_k<<<1, 64, 0, stream>>>(w1, w2, w3, fw);
  support_k<<<N_NODES, 128, 0, stream>>>(X, gw, sup);
  // deg chain (fp32, channel-independent): rc = Hc@1 ; v1 = Hb@rc ; deg = Ha@v1
  rc_from_A_k<<<N_NODES / 4, 256, 0, stream>>>(A, fw, rc);
  matvecA_k<<<N_NODES / 4, 256, 0, stream>>>(A, fw, 16, rc, v1);
  matvecA_k<<<N_NODES / 4, 256, 0, stream>>>(A, fw, 0, v1, deg);

  for (int c0 = 0; c0 < 4; c0 += nc) {
    hipMemsetAsync(cn0, 0, 2L * nc * 128 * sizeof(float), stream);
    // Ha/Hb/Hc split row-major, one A pass
    mix3_k<<<(int)(NNE4 / 256), 256, 0, stream>>>((const float4*)A, fw,
                                                  HaH, HaL, HbH, HbL, HcH, HcL,
                                                  c0, nc);
    // supd + dvec + VT split + cn0, fused
    supdT_k<<<dim3(64, 4, nc), 256, 0, stream>>>(sup, deg, dvec, supd,
                                                 VTH, VTL, cn0, c0);
    // T0 = Hc @ VT
    gemm_thin_k<<<dim3(kc, 16, nc), 256, 0, stream>>>(HcH, HcL, VTH, VTL, Mtmp, kper);
    combineT_k<<<dim3(64, 4, nc), 256, 0, stream>>>(Mtmp, nc, kc, cn0, cn1, T0H, T0L);
    // T1 = Hb @ T0'
    gemm_thin_k<<<dim3(kc, 16, nc), 256, 0, stream>>>(HbH, HbL, T0H, T0L, Mtmp, kper);
    combineT_k<<<dim3(64, 4, nc), 256, 0, stream>>>(Mtmp, nc, kc, cn1, nullptr, T1H, T1L);
    // T2 = Ha @ T1'  (fp32 partials)
    gemm_thin_k<<<dim3(kc, 16, nc), 256, 0, stream>>>(HaH, HaL, T1H, T1L, Mtmp, kper);
    // out = relu( d*(T2*inv + supd) + b )
    final_k<<<dim3(256, nc), 256, 0, stream>>>((const float4*)Mtmp,
                                               (const float4*)supd, dvec,
                                               cn0, cn1, gb, out, c0, nc, kc);
  }
}